// Round 1
// baseline (328.244 us; speedup 1.0000x reference)
//
#include <hip/hip_runtime.h>
#include <math.h>

// Problem constants (match reference)
#define BB 32
#define SS 52
#define AA 3
#define CC 80
// per-anchor pred row = C+5 = 85 floats; per-cell = 255 floats

constexpr int N_CELL = BB * SS * SS;        // 86528
constexpr int N_ANCH = N_CELL * AA;         // 259584

// ws layout (floats):
// [0] sum obj_f
// [1] sum noobj_f
// [2] sum bce * noobj_f
// [3] sum ce  * obj_f
// [4] sum sq  * obj_f
// [5] sum objterm * obj_f

__global__ void yolo_init_ws(float* __restrict__ ws) {
    if (threadIdx.x < 8) ws[threadIdx.x] = 0.0f;
}

__global__ __launch_bounds__(256) void yolo_main(
    const float* __restrict__ target,
    const float* __restrict__ pred,
    const float* __restrict__ anchors,
    float* __restrict__ ws)
{
    int n = blockIdx.x * blockDim.x + threadIdx.x;

    float s_obj = 0.f, s_noobj = 0.f, s_bce = 0.f, s_ce = 0.f, s_sq = 0.f, s_objt = 0.f;

    if (n < N_ANCH) {
        int cell = n / 3;
        int a    = n - cell * 3;
        const float* t = target + (size_t)n * 6;
        const float* p = pred + (size_t)cell * 255 + (size_t)a * 85;

        float y = t[0];
        float l = p[0];  // objectness logit

        if (y == 0.0f) {
            // no-object BCE from logits
            float bce = fmaxf(l, 0.0f) - l * y + log1pf(expf(-fabsf(l)));
            s_noobj = 1.0f;
            s_bce   = bce;
        } else if (y == 1.0f) {
            s_obj = 1.0f;

            // ---- class sparse CE (logsumexp over 80 classes) ----
            const float* cl = p + 5;
            float mx = -INFINITY;
            #pragma unroll 4
            for (int c = 0; c < CC; ++c) mx = fmaxf(mx, cl[c]);
            float se = 0.0f;
            #pragma unroll 4
            for (int c = 0; c < CC; ++c) se += expf(cl[c] - mx);
            int label = (int)t[5];
            float ce = (mx + logf(se)) - cl[label];
            s_ce = ce;

            // ---- box MSE in transformed space ----
            float aw = anchors[a * 2 + 0];
            float ah = anchors[a * 2 + 1];
            float px = 1.0f / (1.0f + expf(-p[1]));   // sigmoid x
            float py = 1.0f / (1.0f + expf(-p[2]));   // sigmoid y
            float pw = p[3];
            float ph = p[4];
            float tx = t[1], ty = t[2];
            float tw = logf(1e-16f + t[3] / aw);
            float th = logf(1e-16f + t[4] / ah);
            float dx = tx - px, dy = ty - py, dw = tw - pw, dh = th - ph;
            s_sq = dx * dx + dy * dy + dw * dw + dh * dh;

            // ---- objectness MSE vs IoU (faithful to reference quirk:
            // decoded pred box vs log-space target box) ----
            float bw = expf(pw) * aw;
            float bh = expf(ph) * ah;
            float b1x1 = px - bw * 0.5f, b1x2 = px + bw * 0.5f;
            float b1y1 = py - bh * 0.5f, b1y2 = py + bh * 0.5f;
            float b2x1 = tx - tw * 0.5f, b2x2 = tx + tw * 0.5f;
            float b2y1 = ty - th * 0.5f, b2y2 = ty + th * 0.5f;
            float iw = fmaxf(fminf(b1x2, b2x2) - fmaxf(b1x1, b2x1), 0.0f);
            float ih = fmaxf(fminf(b1y2, b2y2) - fmaxf(b1y1, b2y1), 0.0f);
            float inter = iw * ih;
            float a1 = fabsf((b1x2 - b1x1) * (b1y2 - b1y1));
            float a2 = fabsf((b2x2 - b2x1) * (b2y2 - b2y1));
            float iou = inter / (a1 + a2 - inter + 1e-6f);
            float d = iou * y - l;  // y == 1 here
            s_objt = d * d;
        }
        // (y other than 0/1 never occurs: target obj flag is exactly 0.0 or 1.0)
    }

    // wave-64 tree reduction
    #pragma unroll
    for (int off = 32; off > 0; off >>= 1) {
        s_obj   += __shfl_down(s_obj,   off, 64);
        s_noobj += __shfl_down(s_noobj, off, 64);
        s_bce   += __shfl_down(s_bce,   off, 64);
        s_ce    += __shfl_down(s_ce,    off, 64);
        s_sq    += __shfl_down(s_sq,    off, 64);
        s_objt  += __shfl_down(s_objt,  off, 64);
    }

    if ((threadIdx.x & 63) == 0) {
        atomicAdd(&ws[0], s_obj);
        atomicAdd(&ws[1], s_noobj);
        atomicAdd(&ws[2], s_bce);
        atomicAdd(&ws[3], s_ce);
        atomicAdd(&ws[4], s_sq);
        atomicAdd(&ws[5], s_objt);
    }
}

__global__ void yolo_final(const float* __restrict__ ws, float* __restrict__ out) {
    if (threadIdx.x == 0 && blockIdx.x == 0) {
        float n_obj   = fmaxf(ws[0], 1.0f);
        float n_noobj = fmaxf(ws[1], 1.0f);
        float noobjloss = ws[2] / n_noobj;
        float classloss = ws[3] / n_obj;
        float boxloss   = ws[4] / (4.0f * n_obj);
        float objloss   = ws[5] / n_obj;
        // L_NOOBJ*noobj + L_CLASS*class + L_BOX*box + L_OBJ*obj
        out[0] = 10.0f * noobjloss + 1.0f * classloss + 10.0f * boxloss + 1.0f * objloss;
    }
}

extern "C" void kernel_launch(void* const* d_in, const int* in_sizes, int n_in,
                              void* d_out, int out_size, void* d_ws, size_t ws_size,
                              hipStream_t stream) {
    const float* target  = (const float*)d_in[0];
    const float* pred    = (const float*)d_in[1];
    const float* anchors = (const float*)d_in[2];
    float* out = (float*)d_out;
    float* ws  = (float*)d_ws;

    hipLaunchKernelGGL(yolo_init_ws, dim3(1), dim3(64), 0, stream, ws);

    int grid = (N_ANCH + 255) / 256;
    hipLaunchKernelGGL(yolo_main, dim3(grid), dim3(256), 0, stream,
                       target, pred, anchors, ws);

    hipLaunchKernelGGL(yolo_final, dim3(1), dim3(64), 0, stream, ws, out);
}

// Round 2
// 36.062 us; speedup vs baseline: 9.1022x; 9.1022x over previous
//
#include <hip/hip_runtime.h>
#include <math.h>

// Problem constants (match reference)
#define BB 32
#define SS 52
#define AA 3
#define CC 80
// per-anchor pred row = C+5 = 85 floats; per-cell = 255 floats

constexpr int N_CELL = BB * SS * SS;        // 86528
constexpr int N_ANCH = N_CELL * AA;         // 259584
constexpr int BLOCK  = 256;
constexpr int NBLK   = (N_ANCH + BLOCK - 1) / BLOCK;   // 1014

// ws layout (floats): per-block partials, 6 per block:
// [blk*6 + 0] sum obj_f
// [blk*6 + 1] sum noobj_f
// [blk*6 + 2] sum bce * noobj_f
// [blk*6 + 3] sum ce  * obj_f
// [blk*6 + 4] sum sq  * obj_f
// [blk*6 + 5] sum objterm * obj_f

__global__ __launch_bounds__(BLOCK) void yolo_main(
    const float* __restrict__ target,
    const float* __restrict__ pred,
    const float* __restrict__ anchors,
    float* __restrict__ ws)
{
    int n = blockIdx.x * blockDim.x + threadIdx.x;

    float s_obj = 0.f, s_noobj = 0.f, s_bce = 0.f, s_ce = 0.f, s_sq = 0.f, s_objt = 0.f;

    if (n < N_ANCH) {
        int cell = n / 3;
        int a    = n - cell * 3;
        const float* t = target + (size_t)n * 6;
        const float* p = pred + (size_t)cell * 255 + (size_t)a * 85;

        float y = t[0];
        float l = p[0];  // objectness logit

        if (y == 0.0f) {
            // no-object BCE from logits (y==0 -> term -l*y drops)
            float bce = fmaxf(l, 0.0f) + log1pf(expf(-fabsf(l)));
            s_noobj = 1.0f;
            s_bce   = bce;
        } else {
            s_obj = 1.0f;

            // ---- class sparse CE (logsumexp over 80 classes) ----
            const float* cl = p + 5;
            float mx = -INFINITY;
            #pragma unroll 4
            for (int c = 0; c < CC; ++c) mx = fmaxf(mx, cl[c]);
            float se = 0.0f;
            #pragma unroll 4
            for (int c = 0; c < CC; ++c) se += expf(cl[c] - mx);
            int label = (int)t[5];
            float ce = (mx + logf(se)) - cl[label];
            s_ce = ce;

            // ---- box MSE in transformed space ----
            float aw = anchors[a * 2 + 0];
            float ah = anchors[a * 2 + 1];
            float px = 1.0f / (1.0f + expf(-p[1]));   // sigmoid x
            float py = 1.0f / (1.0f + expf(-p[2]));   // sigmoid y
            float pw = p[3];
            float ph = p[4];
            float tx = t[1], ty = t[2];
            float tw = logf(1e-16f + t[3] / aw);
            float th = logf(1e-16f + t[4] / ah);
            float dx = tx - px, dy = ty - py, dw = tw - pw, dh = th - ph;
            s_sq = dx * dx + dy * dy + dw * dw + dh * dh;

            // ---- objectness MSE vs IoU (faithful to reference quirk:
            // decoded pred box vs log-space target box) ----
            float bw = expf(pw) * aw;
            float bh = expf(ph) * ah;
            float b1x1 = px - bw * 0.5f, b1x2 = px + bw * 0.5f;
            float b1y1 = py - bh * 0.5f, b1y2 = py + bh * 0.5f;
            float b2x1 = tx - tw * 0.5f, b2x2 = tx + tw * 0.5f;
            float b2y1 = ty - th * 0.5f, b2y2 = ty + th * 0.5f;
            float iw = fmaxf(fminf(b1x2, b2x2) - fmaxf(b1x1, b2x1), 0.0f);
            float ih = fmaxf(fminf(b1y2, b2y2) - fmaxf(b1y1, b2y1), 0.0f);
            float inter = iw * ih;
            float a1 = fabsf((b1x2 - b1x1) * (b1y2 - b1y1));
            float a2 = fabsf((b2x2 - b2x1) * (b2y2 - b2y1));
            float iou = inter / (a1 + a2 - inter + 1e-6f);
            float d = iou - l;  // y == 1 here
            s_objt = d * d;
        }
    }

    // wave-64 tree reduction
    #pragma unroll
    for (int off = 32; off > 0; off >>= 1) {
        s_obj   += __shfl_down(s_obj,   off, 64);
        s_noobj += __shfl_down(s_noobj, off, 64);
        s_bce   += __shfl_down(s_bce,   off, 64);
        s_ce    += __shfl_down(s_ce,    off, 64);
        s_sq    += __shfl_down(s_sq,    off, 64);
        s_objt  += __shfl_down(s_objt,  off, 64);
    }

    // block reduction through LDS: 4 waves -> 1 set of partials, no atomics
    __shared__ float red[4][6];
    int wave = threadIdx.x >> 6;
    if ((threadIdx.x & 63) == 0) {
        red[wave][0] = s_obj;  red[wave][1] = s_noobj; red[wave][2] = s_bce;
        red[wave][3] = s_ce;   red[wave][4] = s_sq;    red[wave][5] = s_objt;
    }
    __syncthreads();
    if (threadIdx.x < 6) {
        float v = red[0][threadIdx.x] + red[1][threadIdx.x]
                + red[2][threadIdx.x] + red[3][threadIdx.x];
        ws[(size_t)blockIdx.x * 6 + threadIdx.x] = v;
    }
}

__global__ __launch_bounds__(256) void yolo_final(const float* __restrict__ ws,
                                                  float* __restrict__ out) {
    float acc[6] = {0.f, 0.f, 0.f, 0.f, 0.f, 0.f};
    for (int b = threadIdx.x; b < NBLK; b += 256) {
        const float* p = ws + (size_t)b * 6;
        #pragma unroll
        for (int k = 0; k < 6; ++k) acc[k] += p[k];
    }
    #pragma unroll
    for (int off = 32; off > 0; off >>= 1) {
        #pragma unroll
        for (int k = 0; k < 6; ++k) acc[k] += __shfl_down(acc[k], off, 64);
    }
    __shared__ float red[4][6];
    int wave = threadIdx.x >> 6;
    if ((threadIdx.x & 63) == 0) {
        #pragma unroll
        for (int k = 0; k < 6; ++k) red[wave][k] = acc[k];
    }
    __syncthreads();
    if (threadIdx.x == 0) {
        float t[6];
        #pragma unroll
        for (int k = 0; k < 6; ++k)
            t[k] = red[0][k] + red[1][k] + red[2][k] + red[3][k];
        float n_obj   = fmaxf(t[0], 1.0f);
        float n_noobj = fmaxf(t[1], 1.0f);
        float noobjloss = t[2] / n_noobj;
        float classloss = t[3] / n_obj;
        float boxloss   = t[4] / (4.0f * n_obj);
        float objloss   = t[5] / n_obj;
        // L_NOOBJ*noobj + L_CLASS*class + L_BOX*box + L_OBJ*obj
        out[0] = 10.0f * noobjloss + 1.0f * classloss + 10.0f * boxloss + 1.0f * objloss;
    }
}

extern "C" void kernel_launch(void* const* d_in, const int* in_sizes, int n_in,
                              void* d_out, int out_size, void* d_ws, size_t ws_size,
                              hipStream_t stream) {
    const float* target  = (const float*)d_in[0];
    const float* pred    = (const float*)d_in[1];
    const float* anchors = (const float*)d_in[2];
    float* out = (float*)d_out;
    float* ws  = (float*)d_ws;

    hipLaunchKernelGGL(yolo_main, dim3(NBLK), dim3(BLOCK), 0, stream,
                       target, pred, anchors, ws);

    hipLaunchKernelGGL(yolo_final, dim3(1), dim3(256), 0, stream, ws, out);
}

// Round 3
// 23.209 us; speedup vs baseline: 14.1432x; 1.5538x over previous
//
#include <hip/hip_runtime.h>
#include <math.h>

// Problem constants (match reference)
#define BB 32
#define SS 52
#define AA 3
#define CC 80
// per-anchor pred row = C+5 = 85 floats; per-cell = 255 floats

constexpr int N_CELL = BB * SS * SS;        // 86528
constexpr int N_ANCH = N_CELL * AA;         // 259584 == 1014 * 256 exactly
constexpr int BLOCK  = 256;
constexpr int NBLK   = N_ANCH / BLOCK;      // 1014

// ws layout (floats): per-block partials, 6 per block:
// [blk*6 + 0] sum obj_f
// [blk*6 + 1] sum noobj_f
// [blk*6 + 2] sum bce * noobj_f
// [blk*6 + 3] sum ce  * obj_f
// [blk*6 + 4] sum sq  * obj_f
// [blk*6 + 5] sum objterm * obj_f

__global__ __launch_bounds__(BLOCK) void yolo_main(
    const float* __restrict__ target,
    const float* __restrict__ pred,
    const float* __restrict__ anchors,
    float* __restrict__ ws)
{
    int n    = blockIdx.x * BLOCK + threadIdx.x;   // always < N_ANCH (exact grid)
    int lane = threadIdx.x & 63;

    int cell = n / 3;
    int a    = n - cell * 3;
    const float* t = target + (size_t)n * 6;
    int poff = cell * 255 + a * 85;               // < 2^25, fits int

    float y = t[0];
    float l = pred[poff];                          // objectness logit (gather)

    float s_obj = 0.f, s_noobj = 0.f, s_bce = 0.f, s_ce = 0.f, s_sq = 0.f, s_objt = 0.f;
    int label_l = 0;                               // this lane's class label (obj lanes only)

    if (y == 0.0f) {
        // no-object BCE from logits (y==0 -> -l*y term drops)
        s_noobj = 1.0f;
        s_bce   = fmaxf(l, 0.0f) + log1pf(expf(-fabsf(l)));
    } else {
        s_obj = 1.0f;
        label_l = (int)t[5];

        // ---- box MSE in transformed space ----
        float aw = anchors[a * 2 + 0];
        float ah = anchors[a * 2 + 1];
        float px = 1.0f / (1.0f + expf(-pred[poff + 1]));   // sigmoid x
        float py = 1.0f / (1.0f + expf(-pred[poff + 2]));   // sigmoid y
        float pw = pred[poff + 3];
        float ph = pred[poff + 4];
        float tx = t[1], ty = t[2];
        float tw = logf(1e-16f + t[3] / aw);
        float th = logf(1e-16f + t[4] / ah);
        float dx = tx - px, dy = ty - py, dw = tw - pw, dh = th - ph;
        s_sq = dx * dx + dy * dy + dw * dw + dh * dh;

        // ---- objectness MSE vs IoU (faithful reference quirk:
        // decoded pred box vs log-space target box) ----
        float bw = expf(pw) * aw;
        float bh = expf(ph) * ah;
        float b1x1 = px - bw * 0.5f, b1x2 = px + bw * 0.5f;
        float b1y1 = py - bh * 0.5f, b1y2 = py + bh * 0.5f;
        float b2x1 = tx - tw * 0.5f, b2x2 = tx + tw * 0.5f;
        float b2y1 = ty - th * 0.5f, b2y2 = ty + th * 0.5f;
        float iw = fmaxf(fminf(b1x2, b2x2) - fmaxf(b1x1, b2x1), 0.0f);
        float ih = fmaxf(fminf(b1y2, b2y2) - fmaxf(b1y1, b2y1), 0.0f);
        float inter = iw * ih;
        float a1 = fabsf((b1x2 - b1x1) * (b1y2 - b1y1));
        float a2 = fabsf((b2x2 - b2x1) * (b2y2 - b2y1));
        float iou = inter / (a1 + a2 - inter + 1e-6f);
        float d = iou - l;   // y == 1 here
        s_objt = d * d;
    }

    // ---- cooperative class CE: all 64 lanes process each obj anchor ----
    // 80-class row is contiguous: lanes 0-63 load cl[lane], lanes 0-15 also
    // load cl[64+lane] -> 2 coalesced loads instead of 80 masked scalar loads.
    unsigned long long m = __ballot(y != 0.0f);
    while (m) {
        int b = __ffsll(m) - 1;
        m &= m - 1;
        int offu  = __shfl(poff, b, 64) + 5;
        int label = __shfl(label_l, b, 64);
        const float* cl = pred + offu;

        float v0 = cl[lane];
        float v1 = (lane < 16) ? cl[64 + lane] : -INFINITY;

        float mx = fmaxf(v0, v1);
        #pragma unroll
        for (int o = 32; o > 0; o >>= 1) mx = fmaxf(mx, __shfl_xor(mx, o, 64));

        float se = expf(v0 - mx) + ((lane < 16) ? expf(v1 - mx) : 0.0f);
        #pragma unroll
        for (int o = 32; o > 0; o >>= 1) se += __shfl_xor(se, o, 64);

        float cand = (label < 64) ? v0 : v1;
        float cll  = __shfl(cand, (label < 64) ? label : (label - 64), 64);

        if (lane == 0) s_ce += (mx + logf(se)) - cll;
    }

    // ---- wave-64 tree reduction ----
    #pragma unroll
    for (int off = 32; off > 0; off >>= 1) {
        s_obj   += __shfl_down(s_obj,   off, 64);
        s_noobj += __shfl_down(s_noobj, off, 64);
        s_bce   += __shfl_down(s_bce,   off, 64);
        s_ce    += __shfl_down(s_ce,    off, 64);
        s_sq    += __shfl_down(s_sq,    off, 64);
        s_objt  += __shfl_down(s_objt,  off, 64);
    }

    // block reduction through LDS: 4 waves -> 1 set of partials, no atomics
    __shared__ float red[4][6];
    int wave = threadIdx.x >> 6;
    if ((threadIdx.x & 63) == 0) {
        red[wave][0] = s_obj;  red[wave][1] = s_noobj; red[wave][2] = s_bce;
        red[wave][3] = s_ce;   red[wave][4] = s_sq;    red[wave][5] = s_objt;
    }
    __syncthreads();
    if (threadIdx.x < 6) {
        float v = red[0][threadIdx.x] + red[1][threadIdx.x]
                + red[2][threadIdx.x] + red[3][threadIdx.x];
        ws[(size_t)blockIdx.x * 6 + threadIdx.x] = v;
    }
}

__global__ __launch_bounds__(256) void yolo_final(const float* __restrict__ ws,
                                                  float* __restrict__ out) {
    float acc[6] = {0.f, 0.f, 0.f, 0.f, 0.f, 0.f};
    for (int b = threadIdx.x; b < NBLK; b += 256) {
        const float* p = ws + (size_t)b * 6;
        #pragma unroll
        for (int k = 0; k < 6; ++k) acc[k] += p[k];
    }
    #pragma unroll
    for (int off = 32; off > 0; off >>= 1) {
        #pragma unroll
        for (int k = 0; k < 6; ++k) acc[k] += __shfl_down(acc[k], off, 64);
    }
    __shared__ float red[4][6];
    int wave = threadIdx.x >> 6;
    if ((threadIdx.x & 63) == 0) {
        #pragma unroll
        for (int k = 0; k < 6; ++k) red[wave][k] = acc[k];
    }
    __syncthreads();
    if (threadIdx.x == 0) {
        float t[6];
        #pragma unroll
        for (int k = 0; k < 6; ++k)
            t[k] = red[0][k] + red[1][k] + red[2][k] + red[3][k];
        float n_obj   = fmaxf(t[0], 1.0f);
        float n_noobj = fmaxf(t[1], 1.0f);
        float noobjloss = t[2] / n_noobj;
        float classloss = t[3] / n_obj;
        float boxloss   = t[4] / (4.0f * n_obj);
        float objloss   = t[5] / n_obj;
        // L_NOOBJ*noobj + L_CLASS*class + L_BOX*box + L_OBJ*obj
        out[0] = 10.0f * noobjloss + 1.0f * classloss + 10.0f * boxloss + 1.0f * objloss;
    }
}

extern "C" void kernel_launch(void* const* d_in, const int* in_sizes, int n_in,
                              void* d_out, int out_size, void* d_ws, size_t ws_size,
                              hipStream_t stream) {
    const float* target  = (const float*)d_in[0];
    const float* pred    = (const float*)d_in[1];
    const float* anchors = (const float*)d_in[2];
    float* out = (float*)d_out;
    float* ws  = (float*)d_ws;

    hipLaunchKernelGGL(yolo_main, dim3(NBLK), dim3(BLOCK), 0, stream,
                       target, pred, anchors, ws);

    hipLaunchKernelGGL(yolo_final, dim3(1), dim3(256), 0, stream, ws, out);
}